// Round 5
// baseline (421.921 us; speedup 1.0000x reference)
//
#include <hip/hip_runtime.h>

typedef __attribute__((ext_vector_type(8))) short bf16x8;
typedef __attribute__((ext_vector_type(4))) float f32x4;

#define MTOK 4096
#define HD 1024
#define FD 2048
#define NEXP 8
#define MAXT 72   // >= sum ceil(cnt_e/128) <= 63+8

struct Ctl {
  int counts[NEXP];
  int cursor[NEXP];
  int totalTiles;
  int _pad[7];
  int4 tileMap[MAXT];        // {expert, growStart, rowsValid, 0}
  int topE[MTOK][2];
  float topW[MTOK][2];
  int pos[MTOK][2];
  int rowTok[2 * MTOK];
};

__device__ __forceinline__ unsigned short f2bf(float f) {
  unsigned int u = __float_as_uint(f);
  unsigned int r = u + 0x7fffu + ((u >> 16) & 1u);   // RNE
  return (unsigned short)(r >> 16);
}
__device__ __forceinline__ float bf2f(unsigned short s) {
  return __uint_as_float(((unsigned int)s) << 16);
}
__device__ __forceinline__ unsigned int pk2(float a, float b) {
  return (unsigned int)f2bf(a) | ((unsigned int)f2bf(b) << 16);
}
// async global->LDS, 16B per lane; LDS dest is wave-uniform base + lane*16 (linear)
__device__ __forceinline__ void gload16(const void* g, void* l) {
  __builtin_amdgcn_global_load_lds(
      (const __attribute__((address_space(1))) void*)g,
      (__attribute__((address_space(3))) void*)l, 16, 0, 0);
}

// ------- transpose + bf16 convert body: [K][N] f32 tile -> [N][K] bf16 (vectorized) -------
__device__ __forceinline__ void tr_body(const float* __restrict__ in,
                                        unsigned short* __restrict__ outp,
                                        int K, int N, int bid, float (*tile)[68]) {
  int ntn = N >> 6, ntk = K >> 6;
  int e = bid / (ntk * ntn);
  int rem = bid % (ntk * ntn);
  int kt = rem / ntn, nt = rem % ntn;
  const float* src = in + (size_t)e * K * N + (size_t)(kt * 64) * N + nt * 64;
  unsigned short* dst = outp + (size_t)e * N * K + (size_t)(nt * 64) * K + kt * 64;
  int t = threadIdx.x;
  int nl4 = t & 15, kr = t >> 4;   // 16 float4-cols x 16 row-groups
#pragma unroll
  for (int i = 0; i < 4; i++) {
    int row = kr + i * 16;
    float4 v = *(const float4*)(src + (size_t)row * N + nl4 * 4);
    *(float4*)&tile[row][nl4 * 4] = v;
  }
  __syncthreads();
  int n2 = t >> 2, kc = (t & 3) * 16;
  unsigned int pk[8];
#pragma unroll
  for (int j = 0; j < 8; j++)
    pk[j] = pk2(tile[kc + 2 * j][n2], tile[kc + 2 * j + 1][n2]);
  *(uint4*)(dst + (size_t)n2 * K + kc) = make_uint4(pk[0], pk[1], pk[2], pk[3]);
  *(uint4*)(dst + (size_t)n2 * K + kc + 8) = make_uint4(pk[4], pk[5], pk[6], pk[7]);
}

// ------- fused prep: tr(w1), tr(w3), cvt(x) in one launch -------
__global__ void k_prep(const float* __restrict__ w1, const float* __restrict__ w3,
                       const float* __restrict__ x,
                       unsigned short* __restrict__ w1t, unsigned short* __restrict__ w3t,
                       unsigned short* __restrict__ xb) {
  __shared__ float tile[64][68];
  int bid = blockIdx.x;
  if (bid < 4096) {
    tr_body(w1, w1t, HD, FD, bid, tile);
  } else if (bid < 8192) {
    tr_body(w3, w3t, HD, FD, bid - 4096, tile);
  } else {
    int i = (bid - 8192) * 256 + threadIdx.x;   // 8 elems/thread, 2048 blocks
    const float4* s = (const float4*)x;
    float4 a = s[i * 2], b = s[i * 2 + 1];
    *(uint4*)(xb + (size_t)i * 8) =
        make_uint4(pk2(a.x, a.y), pk2(a.z, a.w), pk2(b.x, b.y), pk2(b.z, b.w));
  }
}

// ------- standalone transpose (w2, after gemm1; reuses w1t space) -------
__global__ void k_tr(const float* __restrict__ in, unsigned short* __restrict__ outp,
                     int K, int N) {
  __shared__ float tile[64][68];
  tr_body(in, outp, K, N, blockIdx.x, tile);
}

// ---------------- router: GEMV + top2, NO global atomics; block 0 zeroes counts ----------
__global__ void k_router(const float* __restrict__ x, const float* __restrict__ gw,
                         Ctl* __restrict__ ctl) {
  if (blockIdx.x == 0 && threadIdx.x < NEXP) ctl->counts[threadIdx.x] = 0;
  int gt = blockIdx.x * 256 + threadIdx.x;
  int tok = gt >> 6;
  int lane = gt & 63;
  const float* xr = x + (size_t)tok * HD;
  float acc[NEXP] = {};
#pragma unroll
  for (int it = 0; it < 4; it++) {
    int h0 = it * 256 + lane * 4;
    float4 xv = *(const float4*)(xr + h0);
    float xs[4] = {xv.x, xv.y, xv.z, xv.w};
#pragma unroll
    for (int j = 0; j < 4; j++) {
      float4 g0 = *(const float4*)(gw + (size_t)(h0 + j) * 8);
      float4 g1 = *(const float4*)(gw + (size_t)(h0 + j) * 8 + 4);
      acc[0] += xs[j] * g0.x; acc[1] += xs[j] * g0.y;
      acc[2] += xs[j] * g0.z; acc[3] += xs[j] * g0.w;
      acc[4] += xs[j] * g1.x; acc[5] += xs[j] * g1.y;
      acc[6] += xs[j] * g1.z; acc[7] += xs[j] * g1.w;
    }
  }
#pragma unroll
  for (int off = 32; off > 0; off >>= 1) {
#pragma unroll
    for (int e = 0; e < NEXP; e++) acc[e] += __shfl_xor(acc[e], off);
  }
  if (lane == 0) {
    float l0 = -1e30f, l1 = -1e30f; int i0 = 0, i1 = 0;
#pragma unroll
    for (int e = 0; e < NEXP; e++) {
      float v = acc[e];
      if (v > l0) { l1 = l0; i1 = i0; l0 = v; i0 = e; }
      else if (v > l1) { l1 = v; i1 = e; }
    }
    float w0 = 1.f / (1.f + __expf(l1 - l0));
    ctl->topE[tok][0] = i0; ctl->topE[tok][1] = i1;
    ctl->topW[tok][0] = w0; ctl->topW[tok][1] = 1.f - w0;
  }
}

// ---------------- count: LDS-hierarchical (64 global atomics total) ----------------
__global__ void k_count(Ctl* __restrict__ ctl) {
  __shared__ int lcnt[NEXP];
  int t = threadIdx.x;
  if (t < NEXP) lcnt[t] = 0;
  __syncthreads();
  int tok = blockIdx.x * 512 + t;
  atomicAdd(&lcnt[ctl->topE[tok][0]], 1);
  atomicAdd(&lcnt[ctl->topE[tok][1]], 1);
  __syncthreads();
  if (t < NEXP && lcnt[t]) atomicAdd(&ctl->counts[t], lcnt[t]);
}

// ---------------- prefix sums + tile map (parallel over 64 threads) ----------------
__global__ void k_setup(Ctl* __restrict__ ctl) {
  int lane = threadIdx.x;
  int myC[NEXP], myOff[NEXP], myTb[NEXP];
  int off = 0, t = 0;
#pragma unroll
  for (int e = 0; e < NEXP; e++) {
    int c = ctl->counts[e];
    myC[e] = c; myOff[e] = off; myTb[e] = t;
    off += c; t += (c + 127) >> 7;
  }
  if (lane < NEXP) ctl->cursor[lane] = myOff[lane];
  if (lane == 0) ctl->totalTiles = t;
  for (int i = lane; i < MAXT; i += 64) {
    int4 v = make_int4(0, 0, 0, 0);
    if (i < t) {
      int e = 0;
#pragma unroll
      for (int q = 1; q < NEXP; q++) if (myTb[q] <= i) e = q;
      int j = i - myTb[e];
      v = make_int4(e, myOff[e] + j * 128, min(128, myC[e] - j * 128), 0);
    }
    ctl->tileMap[i] = v;
  }
}

// ---------------- scatter: LDS rank + one range-reserve atomic per expert per block ----------
__global__ void k_scatter(Ctl* __restrict__ ctl) {
  __shared__ int lcur[NEXP];
  __shared__ int gbase[NEXP];
  int t = threadIdx.x;
  int tok = blockIdx.x * 512 + t;
  if (t < NEXP) lcur[t] = 0;
  __syncthreads();
  int e0 = ctl->topE[tok][0];
  int e1 = ctl->topE[tok][1];
  int r0 = atomicAdd(&lcur[e0], 1);
  int r1 = atomicAdd(&lcur[e1], 1);
  __syncthreads();
  if (t < NEXP) gbase[t] = lcur[t] ? atomicAdd(&ctl->cursor[t], lcur[t]) : 0;
  __syncthreads();
  int p0 = gbase[e0] + r0;
  int p1 = gbase[e1] + r1;
  ctl->rowTok[p0] = tok; ctl->pos[tok][0] = p0;
  ctl->rowTok[p1] = tok; ctl->pos[tok][1] = p1;
}

// ======== GEMM1: h = silu(x@w1[e]) * (x@w3[e]); 2-stage double-buffer (proven 91us) ========
// tile 128x128, BK=32, 512 thr (8 waves 2x4)
__launch_bounds__(512, 2)
__global__ void k_gemm1(const unsigned short* __restrict__ xb,
                        const unsigned short* __restrict__ w1t,
                        const unsigned short* __restrict__ w3t,
                        unsigned short* __restrict__ hg,
                        const Ctl* __restrict__ ctl) {
  __shared__ __align__(1024) unsigned char lds[2][3][8192];
  int nwg = MAXT * (FD / 128);
  int bid = blockIdx.x;
  int swz = (bid & 7) * (nwg >> 3) + (bid >> 3);   // bijective XCD swizzle (nwg%8==0)
  int rt = swz % MAXT, ct = swz / MAXT;
  int4 tm = ctl->tileMap[rt];
  if (tm.z == 0) return;
  int e = tm.x, grow0 = tm.y, nrows = tm.z;
  int t = threadIdx.x;

  // staging: thread t -> LDS slot (row=t>>2, chunk=t&3); source chunk XOR-swizzled
  int r = t >> 2;
  int cl = (t & 3) ^ ((r >> 1) & 3);
  int rA = min(r, nrows - 1);
  int tok = ctl->rowTok[grow0 + rA];
  const unsigned short* aG  = xb  + (size_t)tok * HD + cl * 8;
  const unsigned short* b1G = w1t + ((size_t)e * FD + ct * 128 + r) * HD + cl * 8;
  const unsigned short* b3G = w3t + ((size_t)e * FD + ct * 128 + r) * HD + cl * 8;
  unsigned char* ldsDstA  = &lds[0][0][t * 16];
  unsigned char* ldsDstB1 = &lds[0][1][t * 16];
  unsigned char* ldsDstB3 = &lds[0][2][t * 16];

  int lane = t & 63, wv = t >> 6, wr = wv >> 2, wc = wv & 3;
  int lm = lane & 15, lk = lane >> 4;
  int aOff[4], bOff[2];
#pragma unroll
  for (int ma = 0; ma < 4; ma++) {
    int row = wr * 64 + ma * 16 + lm;
    aOff[ma] = row * 64 + ((lk ^ ((row >> 1) & 3)) << 4);
  }
#pragma unroll
  for (int nb = 0; nb < 2; nb++) {
    int row = wc * 32 + nb * 16 + lm;
    bOff[nb] = row * 64 + ((lk ^ ((row >> 1) & 3)) << 4);
  }

  f32x4 accA[4][2] = {};
  f32x4 accC[4][2] = {};

  const int NK = HD / 32;
  gload16(aG, ldsDstA); gload16(b1G, ldsDstB1); gload16(b3G, ldsDstB3);
  for (int kt = 0; kt < NK; kt++) {
    int b = kt & 1;
    if (kt + 1 < NK) {
      size_t ko = (size_t)(kt + 1) * 32;
      int nbuf = b ^ 1;
      gload16(aG + ko,  ldsDstA  + nbuf * 3 * 8192);
      gload16(b1G + ko, ldsDstB1 + nbuf * 3 * 8192);
      gload16(b3G + ko, ldsDstB3 + nbuf * 3 * 8192);
      asm volatile("s_waitcnt vmcnt(3)" ::: "memory");   // cur tile landed; next 3 in flight
    } else {
      asm volatile("s_waitcnt vmcnt(0)" ::: "memory");
    }
    __builtin_amdgcn_s_barrier();
    asm volatile("" ::: "memory");
    const unsigned char* pA  = &lds[b][0][0];
    const unsigned char* pB1 = &lds[b][1][0];
    const unsigned char* pB3 = &lds[b][2][0];
    bf16x8 af[4], bf1[2], bf3[2];
#pragma unroll
    for (int ma = 0; ma < 4; ma++) af[ma] = *(const bf16x8*)(pA + aOff[ma]);
#pragma unroll
    for (int nb = 0; nb < 2; nb++) {
      bf1[nb] = *(const bf16x8*)(pB1 + bOff[nb]);
      bf3[nb] = *(const bf16x8*)(pB3 + bOff[nb]);
    }
#pragma unroll
    for (int nb = 0; nb < 2; nb++)
#pragma unroll
      for (int ma = 0; ma < 4; ma++) {
        accA[ma][nb] = __builtin_amdgcn_mfma_f32_16x16x32_bf16(af[ma], bf1[nb], accA[ma][nb], 0, 0, 0);
        accC[ma][nb] = __builtin_amdgcn_mfma_f32_16x16x32_bf16(af[ma], bf3[nb], accC[ma][nb], 0, 0, 0);
      }
    asm volatile("" ::: "memory");
    __builtin_amdgcn_s_barrier();   // all waves done reading buf b before it's restaged
  }

#pragma unroll
  for (int ma = 0; ma < 4; ma++) {
    int lrowBase = wr * 64 + ma * 16 + lk * 4;
#pragma unroll
    for (int nb = 0; nb < 2; nb++) {
      int col = ct * 128 + wc * 32 + nb * 16 + lm;
#pragma unroll
      for (int rr = 0; rr < 4; rr++) {
        int lrow = lrowBase + rr;
        if (lrow < nrows) {
          float a = accA[ma][nb][rr];
          float c = accC[ma][nb][rr];
          float hv = a / (1.f + __expf(-a)) * c;   // silu(a)*c
          hg[(size_t)(grow0 + lrow) * FD + col] = f2bf(hv);
        }
      }
    }
  }
}

// ======== GEMM2: og = h @ w2t[e]; tile 128x64, 256 thr (4 waves 2x2), 2-stage ========
// 1152 blocks -> no scheduling tail; 24KB LDS -> ~6 blocks/CU
__launch_bounds__(256, 2)
__global__ void k_gemm2(const unsigned short* __restrict__ hg,
                        const unsigned short* __restrict__ w2t,
                        unsigned short* __restrict__ og,
                        const Ctl* __restrict__ ctl) {
  __shared__ __align__(1024) unsigned char lds[2][12288];   // per buf: A 8KB | B 4KB
  int nwg = MAXT * (HD / 64);   // 72*16 = 1152
  int bid = blockIdx.x;
  int swz = (bid & 7) * (nwg >> 3) + (bid >> 3);
  int rt = swz % MAXT, ct = swz / MAXT;
  int4 tm = ctl->tileMap[rt];
  if (tm.z == 0) return;
  int e = tm.x, grow0 = tm.y, nrows = tm.z;
  int t = threadIdx.x;

  // A: 128 rows x 32k -> 512 slots; thread t covers slot t (rows 0-63) and slot 256+t (rows 64-127)
  int rA0 = t >> 2, rA1 = 64 + (t >> 2);
  int cl0 = (t & 3) ^ ((rA0 >> 1) & 3);
  int cl1 = (t & 3) ^ ((rA1 >> 1) & 3);
  const unsigned short* aG0 = hg + (size_t)(grow0 + min(rA0, nrows - 1)) * FD + cl0 * 8;
  const unsigned short* aG1 = hg + (size_t)(grow0 + min(rA1, nrows - 1)) * FD + cl1 * 8;
  // B: 64 rows x 32k -> 256 slots, thread t -> slot t
  int rB = t >> 2;
  int clB = (t & 3) ^ ((rB >> 1) & 3);
  const unsigned short* bG = w2t + ((size_t)e * HD + ct * 64 + rB) * FD + clB * 8;
  unsigned char* ldsA0 = &lds[0][t * 16];
  unsigned char* ldsA1 = &lds[0][4096 + t * 16];
  unsigned char* ldsB  = &lds[0][8192 + t * 16];

  int lane = t & 63, wv = t >> 6, wr = wv >> 1, wc = wv & 1;
  int lm = lane & 15, lk = lane >> 4;
  int aOff[4], bOff[2];
#pragma unroll
  for (int ma = 0; ma < 4; ma++) {
    int row = wr * 64 + ma * 16 + lm;
    aOff[ma] = row * 64 + ((lk ^ ((row >> 1) & 3)) << 4);
  }
#pragma unroll
  for (int nb = 0; nb < 2; nb++) {
    int row = wc * 32 + nb * 16 + lm;
    bOff[nb] = 8192 + row * 64 + ((lk ^ ((row >> 1) & 3)) << 4);
  }

  f32x4 acc[4][2] = {};
  const int NK = FD / 32;   // 64
  gload16(aG0, ldsA0); gload16(aG1, ldsA1); gload16(bG, ldsB);
  for (int kt = 0; kt < NK; kt++) {
    int b = kt & 1;
    if (kt + 1 < NK) {
      size_t ko = (size_t)(kt + 1) * 32;
      int nbuf = b ^ 1;
      gload16(aG0 + ko, ldsA0 + nbuf * 12288);
      gload16(aG1 + ko, ldsA1 + nbuf * 12288);
      gload16(bG + ko,  ldsB  + nbuf * 12288);
      asm volatile("s_waitcnt vmcnt(3)" ::: "memory");
    } else {
      asm volatile("s_waitcnt vmcnt(0)" ::: "memory");
    }
    __builtin_amdgcn_s_barrier();
    asm volatile("" ::: "memory");
    const unsigned char* pL = &lds[b][0];
    bf16x8 af[4], bfr[2];
#pragma unroll
    for (int ma = 0; ma < 4; ma++) af[ma] = *(const bf16x8*)(pL + aOff[ma]);
#pragma unroll
    for (int nb = 0; nb < 2; nb++) bfr[nb] = *(const bf16x8*)(pL + bOff[nb]);
#pragma unroll
    for (int nb = 0; nb < 2; nb++)
#pragma unroll
      for (int ma = 0; ma < 4; ma++)
        acc[ma][nb] = __builtin_amdgcn_mfma_f32_16x16x32_bf16(af[ma], bfr[nb], acc[ma][nb], 0, 0, 0);
    asm volatile("" ::: "memory");
    __builtin_amdgcn_s_barrier();
  }

#pragma unroll
  for (int ma = 0; ma < 4; ma++) {
    int lrowBase = wr * 64 + ma * 16 + lk * 4;
#pragma unroll
    for (int nb = 0; nb < 2; nb++) {
      int col = ct * 64 + wc * 32 + nb * 16 + lm;
#pragma unroll
      for (int rr = 0; rr < 4; rr++) {
        int lrow = lrowBase + rr;
        if (lrow < nrows)
          og[(size_t)(grow0 + lrow) * HD + col] = f2bf(acc[ma][nb][rr]);
      }
    }
  }
}

// ---------------- combine ----------------
__global__ void k_combine(const unsigned short* __restrict__ og, float* __restrict__ out,
                          const Ctl* __restrict__ ctl) {
  int tok = blockIdx.x;
  int tid = threadIdx.x;
  int p0 = ctl->pos[tok][0], p1 = ctl->pos[tok][1];
  float w0 = ctl->topW[tok][0], w1 = ctl->topW[tok][1];
  uint2 a = *(const uint2*)(og + (size_t)p0 * HD + tid * 4);
  uint2 b = *(const uint2*)(og + (size_t)p1 * HD + tid * 4);
  float4 o;
  o.x = w0 * bf2f((unsigned short)(a.x & 0xffffu)) + w1 * bf2f((unsigned short)(b.x & 0xffffu));
  o.y = w0 * bf2f((unsigned short)(a.x >> 16))     + w1 * bf2f((unsigned short)(b.x >> 16));
  o.z = w0 * bf2f((unsigned short)(a.y & 0xffffu)) + w1 * bf2f((unsigned short)(b.y & 0xffffu));
  o.w = w0 * bf2f((unsigned short)(a.y >> 16))     + w1 * bf2f((unsigned short)(b.y >> 16));
  *(float4*)(out + (size_t)tok * HD + tid * 4) = o;
}

extern "C" void kernel_launch(void* const* d_in, const int* in_sizes, int n_in,
                              void* d_out, int out_size, void* d_ws, size_t ws_size,
                              hipStream_t stream) {
  const float* x  = (const float*)d_in[0];   // [4,1024,1024]
  const float* gw = (const float*)d_in[1];   // [1024,8]
  const float* w1 = (const float*)d_in[2];   // [8,1024,2048]
  const float* w2 = (const float*)d_in[3];   // [8,2048,1024]
  const float* w3 = (const float*)d_in[4];   // [8,1024,2048]
  float* out = (float*)d_out;

  char* ws = (char*)d_ws;
  unsigned short* hg  = (unsigned short*)(ws);                         // 32 MB
  unsigned short* og  = (unsigned short*)(ws + (size_t)(32u << 20));   // 16 MB
  unsigned short* xb  = (unsigned short*)(ws + (size_t)(48u << 20));   // 8 MB
  unsigned short* wAt = (unsigned short*)(ws + (size_t)(56u << 20));   // 32 MB (w1t, then w2t)
  unsigned short* wBt = (unsigned short*)(ws + (size_t)(88u << 20));   // 32 MB (w3t)
  Ctl* ctl = (Ctl*)(ws + (size_t)(120u << 20));

  k_prep<<<dim3(8192 + 2048), 256, 0, stream>>>(w1, w3, x, wAt, wBt, xb);
  k_router<<<dim3(MTOK / 4), 256, 0, stream>>>(x, gw, ctl);
  k_count<<<dim3(MTOK / 512), 512, 0, stream>>>(ctl);
  k_setup<<<1, 64, 0, stream>>>(ctl);
  k_scatter<<<dim3(MTOK / 512), 512, 0, stream>>>(ctl);
  k_gemm1<<<dim3(MAXT * (FD / 128)), 512, 0, stream>>>(xb, wAt, wBt, hg, ctl);
  k_tr<<<dim3(8 * 32 * 16), 256, 0, stream>>>(w2, wAt, FD, HD);   // w2t reuses w1t space
  k_gemm2<<<dim3(MAXT * (HD / 64)), 256, 0, stream>>>(hg, wAt, og, ctl);
  k_combine<<<dim3(MTOK), 256, 0, stream>>>(og, out, ctl);
}

// Round 6
// 388.018 us; speedup vs baseline: 1.0874x; 1.0874x over previous
//
#include <hip/hip_runtime.h>

typedef __attribute__((ext_vector_type(8))) short bf16x8;
typedef __attribute__((ext_vector_type(4))) float f32x4;

#define MTOK 4096
#define HD 1024
#define FD 2048
#define NEXP 8
#define MAXT 72   // >= sum ceil(cnt_e/128) <= 63+8

struct Ctl {
  int counts[NEXP];
  int cursor[NEXP];
  int totalTiles;
  int _pad[7];
  int4 tileMap[MAXT];        // {expert, growStart, rowsValid, 0}
  int topE[MTOK][2];
  float topW[MTOK][2];
  int pos[MTOK][2];
  int rowTok[2 * MTOK];
};

__device__ __forceinline__ unsigned short f2bf(float f) {
  unsigned int u = __float_as_uint(f);
  unsigned int r = u + 0x7fffu + ((u >> 16) & 1u);   // RNE
  return (unsigned short)(r >> 16);
}
__device__ __forceinline__ float bf2f(unsigned short s) {
  return __uint_as_float(((unsigned int)s) << 16);
}
__device__ __forceinline__ unsigned int pk2(float a, float b) {
  return (unsigned int)f2bf(a) | ((unsigned int)f2bf(b) << 16);
}
// async global->LDS, 16B per lane; LDS dest is wave-uniform base + lane*16 (linear)
__device__ __forceinline__ void gload16(const void* g, void* l) {
  __builtin_amdgcn_global_load_lds(
      (const __attribute__((address_space(1))) void*)g,
      (__attribute__((address_space(3))) void*)l, 16, 0, 0);
}

// ------- transpose + bf16 convert body: [K][N] f32 tile -> [N][K] bf16 -------
// read phase staggered per kc-group: 4-way bank conflict -> 2-way (free)
__device__ __forceinline__ void tr_body(const float* __restrict__ in,
                                        unsigned short* __restrict__ outp,
                                        int K, int N, int bid, float (*tile)[68]) {
  int ntn = N >> 6, ntk = K >> 6;
  int e = bid / (ntk * ntn);
  int rem = bid % (ntk * ntn);
  int kt = rem / ntn, nt = rem % ntn;
  const float* src = in + (size_t)e * K * N + (size_t)(kt * 64) * N + nt * 64;
  unsigned short* dst = outp + (size_t)e * N * K + (size_t)(nt * 64) * K + kt * 64;
  int t = threadIdx.x;
  int nl4 = t & 15, kr = t >> 4;   // 16 float4-cols x 16 row-groups
#pragma unroll
  for (int i = 0; i < 4; i++) {
    int row = kr + i * 16;
    float4 v = *(const float4*)(src + (size_t)row * N + nl4 * 4);
    *(float4*)&tile[row][nl4 * 4] = v;
  }
  __syncthreads();
  int n2 = t >> 2, kc = (t & 3) * 16;
  int st = (t & 3) * 2;                  // stagger: concurrent kc-groups hit different banks
  unsigned int pk[8];
#pragma unroll
  for (int j = 0; j < 8; j++) {
    int jj = (j + st) & 7;
    pk[jj] = pk2(tile[kc + 2 * jj][n2], tile[kc + 2 * jj + 1][n2]);
  }
  *(uint4*)(dst + (size_t)n2 * K + kc) = make_uint4(pk[0], pk[1], pk[2], pk[3]);
  *(uint4*)(dst + (size_t)n2 * K + kc + 8) = make_uint4(pk[4], pk[5], pk[6], pk[7]);
}

// ------- fused prep: tr(w1), tr(w3) in one launch -------
__global__ void k_prep(const float* __restrict__ w1, const float* __restrict__ w3,
                       unsigned short* __restrict__ w1t, unsigned short* __restrict__ w3t) {
  __shared__ float tile[64][68];
  int bid = blockIdx.x;
  if (bid < 4096) {
    tr_body(w1, w1t, HD, FD, bid, tile);
  } else {
    tr_body(w3, w3t, HD, FD, bid - 4096, tile);
  }
}

// ------- standalone transpose (w2, after gemm1; reuses w1t space) -------
__global__ void k_tr(const float* __restrict__ in, unsigned short* __restrict__ outp,
                     int K, int N) {
  __shared__ float tile[64][68];
  tr_body(in, outp, K, N, blockIdx.x, tile);
}

// ------- router: GEMV + top2 + x->bf16 convert fused; block 0 zeroes counts -------
__global__ void k_router(const float* __restrict__ x, const float* __restrict__ gw,
                         unsigned short* __restrict__ xb, Ctl* __restrict__ ctl) {
  if (blockIdx.x == 0 && threadIdx.x < NEXP) ctl->counts[threadIdx.x] = 0;
  int gt = blockIdx.x * 256 + threadIdx.x;
  int tok = gt >> 6;
  int lane = gt & 63;
  const float* xr = x + (size_t)tok * HD;
  float acc[NEXP] = {};
#pragma unroll
  for (int it = 0; it < 4; it++) {
    int h0 = it * 256 + lane * 4;
    float4 xv = *(const float4*)(xr + h0);
    // fused x -> bf16 store (coalesced 8B/lane)
    *(uint2*)(xb + (size_t)tok * HD + h0) = make_uint2(pk2(xv.x, xv.y), pk2(xv.z, xv.w));
    float xs[4] = {xv.x, xv.y, xv.z, xv.w};
#pragma unroll
    for (int j = 0; j < 4; j++) {
      float4 g0 = *(const float4*)(gw + (size_t)(h0 + j) * 8);
      float4 g1 = *(const float4*)(gw + (size_t)(h0 + j) * 8 + 4);
      acc[0] += xs[j] * g0.x; acc[1] += xs[j] * g0.y;
      acc[2] += xs[j] * g0.z; acc[3] += xs[j] * g0.w;
      acc[4] += xs[j] * g1.x; acc[5] += xs[j] * g1.y;
      acc[6] += xs[j] * g1.z; acc[7] += xs[j] * g1.w;
    }
  }
#pragma unroll
  for (int off = 32; off > 0; off >>= 1) {
#pragma unroll
    for (int e = 0; e < NEXP; e++) acc[e] += __shfl_xor(acc[e], off);
  }
  if (lane == 0) {
    float l0 = -1e30f, l1 = -1e30f; int i0 = 0, i1 = 0;
#pragma unroll
    for (int e = 0; e < NEXP; e++) {
      float v = acc[e];
      if (v > l0) { l1 = l0; i1 = i0; l0 = v; i0 = e; }
      else if (v > l1) { l1 = v; i1 = e; }
    }
    float w0 = 1.f / (1.f + __expf(l1 - l0));
    ctl->topE[tok][0] = i0; ctl->topE[tok][1] = i1;
    ctl->topW[tok][0] = w0; ctl->topW[tok][1] = 1.f - w0;
  }
}

// ---------------- count: LDS-hierarchical (64 global atomics total) ----------------
__global__ void k_count(Ctl* __restrict__ ctl) {
  __shared__ int lcnt[NEXP];
  int t = threadIdx.x;
  if (t < NEXP) lcnt[t] = 0;
  __syncthreads();
  int tok = blockIdx.x * 512 + t;
  atomicAdd(&lcnt[ctl->topE[tok][0]], 1);
  atomicAdd(&lcnt[ctl->topE[tok][1]], 1);
  __syncthreads();
  if (t < NEXP && lcnt[t]) atomicAdd(&ctl->counts[t], lcnt[t]);
}

// ---------------- prefix sums + tile map (parallel over 64 threads) ----------------
__global__ void k_setup(Ctl* __restrict__ ctl) {
  int lane = threadIdx.x;
  int myC[NEXP], myOff[NEXP], myTb[NEXP];
  int off = 0, t = 0;
#pragma unroll
  for (int e = 0; e < NEXP; e++) {
    int c = ctl->counts[e];
    myC[e] = c; myOff[e] = off; myTb[e] = t;
    off += c; t += (c + 127) >> 7;
  }
  if (lane < NEXP) ctl->cursor[lane] = myOff[lane];
  if (lane == 0) ctl->totalTiles = t;
  for (int i = lane; i < MAXT; i += 64) {
    int4 v = make_int4(0, 0, 0, 0);
    if (i < t) {
      int e = 0;
#pragma unroll
      for (int q = 1; q < NEXP; q++) if (myTb[q] <= i) e = q;
      int j = i - myTb[e];
      v = make_int4(e, myOff[e] + j * 128, min(128, myC[e] - j * 128), 0);
    }
    ctl->tileMap[i] = v;
  }
}

// ---------------- scatter: LDS rank + one range-reserve atomic per expert per block ----------
__global__ void k_scatter(Ctl* __restrict__ ctl) {
  __shared__ int lcur[NEXP];
  __shared__ int gbase[NEXP];
  int t = threadIdx.x;
  int tok = blockIdx.x * 512 + t;
  if (t < NEXP) lcur[t] = 0;
  __syncthreads();
  int e0 = ctl->topE[tok][0];
  int e1 = ctl->topE[tok][1];
  int r0 = atomicAdd(&lcur[e0], 1);
  int r1 = atomicAdd(&lcur[e1], 1);
  __syncthreads();
  if (t < NEXP) gbase[t] = lcur[t] ? atomicAdd(&ctl->cursor[t], lcur[t]) : 0;
  __syncthreads();
  int p0 = gbase[e0] + r0;
  int p1 = gbase[e1] + r1;
  ctl->rowTok[p0] = tok; ctl->pos[tok][0] = p0;
  ctl->rowTok[p1] = tok; ctl->pos[tok][1] = p1;
}

// ======== GEMM1: h = silu(x@w1[e]) * (x@w3[e]); 2-stage double-buffer (proven 91us) ========
// tile 128x128, BK=32, 512 thr (8 waves 2x4)
__launch_bounds__(512, 2)
__global__ void k_gemm1(const unsigned short* __restrict__ xb,
                        const unsigned short* __restrict__ w1t,
                        const unsigned short* __restrict__ w3t,
                        unsigned short* __restrict__ hg,
                        const Ctl* __restrict__ ctl) {
  __shared__ __align__(1024) unsigned char lds[2][3][8192];
  int nwg = MAXT * (FD / 128);
  int bid = blockIdx.x;
  int swz = (bid & 7) * (nwg >> 3) + (bid >> 3);   // bijective XCD swizzle (nwg%8==0)
  int rt = swz % MAXT, ct = swz / MAXT;
  int4 tm = ctl->tileMap[rt];
  if (tm.z == 0) return;
  int e = tm.x, grow0 = tm.y, nrows = tm.z;
  int t = threadIdx.x;

  // staging: thread t -> LDS slot (row=t>>2, chunk=t&3); source chunk XOR-swizzled
  int r = t >> 2;
  int cl = (t & 3) ^ ((r >> 1) & 3);
  int rA = min(r, nrows - 1);
  int tok = ctl->rowTok[grow0 + rA];
  const unsigned short* aG  = xb  + (size_t)tok * HD + cl * 8;
  const unsigned short* b1G = w1t + ((size_t)e * FD + ct * 128 + r) * HD + cl * 8;
  const unsigned short* b3G = w3t + ((size_t)e * FD + ct * 128 + r) * HD + cl * 8;
  unsigned char* ldsDstA  = &lds[0][0][t * 16];
  unsigned char* ldsDstB1 = &lds[0][1][t * 16];
  unsigned char* ldsDstB3 = &lds[0][2][t * 16];

  int lane = t & 63, wv = t >> 6, wr = wv >> 2, wc = wv & 3;
  int lm = lane & 15, lk = lane >> 4;
  int aOff[4], bOff[2];
#pragma unroll
  for (int ma = 0; ma < 4; ma++) {
    int row = wr * 64 + ma * 16 + lm;
    aOff[ma] = row * 64 + ((lk ^ ((row >> 1) & 3)) << 4);
  }
#pragma unroll
  for (int nb = 0; nb < 2; nb++) {
    int row = wc * 32 + nb * 16 + lm;
    bOff[nb] = row * 64 + ((lk ^ ((row >> 1) & 3)) << 4);
  }

  f32x4 accA[4][2] = {};
  f32x4 accC[4][2] = {};

  const int NK = HD / 32;
  gload16(aG, ldsDstA); gload16(b1G, ldsDstB1); gload16(b3G, ldsDstB3);
  for (int kt = 0; kt < NK; kt++) {
    int b = kt & 1;
    if (kt + 1 < NK) {
      size_t ko = (size_t)(kt + 1) * 32;
      int nbuf = b ^ 1;
      gload16(aG + ko,  ldsDstA  + nbuf * 3 * 8192);
      gload16(b1G + ko, ldsDstB1 + nbuf * 3 * 8192);
      gload16(b3G + ko, ldsDstB3 + nbuf * 3 * 8192);
      asm volatile("s_waitcnt vmcnt(3)" ::: "memory");   // cur tile landed; next 3 in flight
    } else {
      asm volatile("s_waitcnt vmcnt(0)" ::: "memory");
    }
    __builtin_amdgcn_s_barrier();
    asm volatile("" ::: "memory");
    const unsigned char* pA  = &lds[b][0][0];
    const unsigned char* pB1 = &lds[b][1][0];
    const unsigned char* pB3 = &lds[b][2][0];
    bf16x8 af[4], bf1[2], bf3[2];
#pragma unroll
    for (int ma = 0; ma < 4; ma++) af[ma] = *(const bf16x8*)(pA + aOff[ma]);
#pragma unroll
    for (int nb = 0; nb < 2; nb++) {
      bf1[nb] = *(const bf16x8*)(pB1 + bOff[nb]);
      bf3[nb] = *(const bf16x8*)(pB3 + bOff[nb]);
    }
#pragma unroll
    for (int nb = 0; nb < 2; nb++)
#pragma unroll
      for (int ma = 0; ma < 4; ma++) {
        accA[ma][nb] = __builtin_amdgcn_mfma_f32_16x16x32_bf16(af[ma], bf1[nb], accA[ma][nb], 0, 0, 0);
        accC[ma][nb] = __builtin_amdgcn_mfma_f32_16x16x32_bf16(af[ma], bf3[nb], accC[ma][nb], 0, 0, 0);
      }
    asm volatile("" ::: "memory");
    __builtin_amdgcn_s_barrier();   // all waves done reading buf b before it's restaged
  }

#pragma unroll
  for (int ma = 0; ma < 4; ma++) {
    int lrowBase = wr * 64 + ma * 16 + lk * 4;
#pragma unroll
    for (int nb = 0; nb < 2; nb++) {
      int col = ct * 128 + wc * 32 + nb * 16 + lm;
#pragma unroll
      for (int rr = 0; rr < 4; rr++) {
        int lrow = lrowBase + rr;
        if (lrow < nrows) {
          float a = accA[ma][nb][rr];
          float c = accC[ma][nb][rr];
          float hv = a / (1.f + __expf(-a)) * c;   // silu(a)*c
          hg[(size_t)(grow0 + lrow) * FD + col] = f2bf(hv);
        }
      }
    }
  }
}

// ======== GEMM2: og = h @ w2t[e]; tile 128x128, 512 thr, 2-stage (R3-proven) ========
__launch_bounds__(512, 2)
__global__ void k_gemm2(const unsigned short* __restrict__ hg,
                        const unsigned short* __restrict__ w2t,
                        unsigned short* __restrict__ og,
                        const Ctl* __restrict__ ctl) {
  __shared__ __align__(1024) unsigned char lds[2][2][8192];
  int nwg = MAXT * (HD / 128);   // 576, %8==0
  int bid = blockIdx.x;
  int swz = (bid & 7) * (nwg >> 3) + (bid >> 3);
  int rt = swz % MAXT, ct = swz / MAXT;
  int4 tm = ctl->tileMap[rt];
  if (tm.z == 0) return;
  int e = tm.x, grow0 = tm.y, nrows = tm.z;
  int t = threadIdx.x;

  int r = t >> 2;
  int cl = (t & 3) ^ ((r >> 1) & 3);
  int rA = min(r, nrows - 1);
  const unsigned short* aG = hg  + (size_t)(grow0 + rA) * FD + cl * 8;
  const unsigned short* bG = w2t + ((size_t)e * HD + ct * 128 + r) * FD + cl * 8;
  unsigned char* ldsDstA = &lds[0][0][t * 16];
  unsigned char* ldsDstB = &lds[0][1][t * 16];

  int lane = t & 63, wv = t >> 6, wr = wv >> 2, wc = wv & 3;
  int lm = lane & 15, lk = lane >> 4;
  int aOff[4], bOff[2];
#pragma unroll
  for (int ma = 0; ma < 4; ma++) {
    int row = wr * 64 + ma * 16 + lm;
    aOff[ma] = row * 64 + ((lk ^ ((row >> 1) & 3)) << 4);
  }
#pragma unroll
  for (int nb = 0; nb < 2; nb++) {
    int row = wc * 32 + nb * 16 + lm;
    bOff[nb] = row * 64 + ((lk ^ ((row >> 1) & 3)) << 4);
  }

  f32x4 acc[4][2] = {};
  const int NK = FD / 32;
  gload16(aG, ldsDstA); gload16(bG, ldsDstB);
  for (int kt = 0; kt < NK; kt++) {
    int b = kt & 1;
    if (kt + 1 < NK) {
      size_t ko = (size_t)(kt + 1) * 32;
      int nbuf = b ^ 1;
      gload16(aG + ko, ldsDstA + nbuf * 2 * 8192);
      gload16(bG + ko, ldsDstB + nbuf * 2 * 8192);
      asm volatile("s_waitcnt vmcnt(2)" ::: "memory");
    } else {
      asm volatile("s_waitcnt vmcnt(0)" ::: "memory");
    }
    __builtin_amdgcn_s_barrier();
    asm volatile("" ::: "memory");
    const unsigned char* pA = &lds[b][0][0];
    const unsigned char* pB = &lds[b][1][0];
    bf16x8 af[4], bfr[2];
#pragma unroll
    for (int ma = 0; ma < 4; ma++) af[ma] = *(const bf16x8*)(pA + aOff[ma]);
#pragma unroll
    for (int nb = 0; nb < 2; nb++) bfr[nb] = *(const bf16x8*)(pB + bOff[nb]);
#pragma unroll
    for (int nb = 0; nb < 2; nb++)
#pragma unroll
      for (int ma = 0; ma < 4; ma++)
        acc[ma][nb] = __builtin_amdgcn_mfma_f32_16x16x32_bf16(af[ma], bfr[nb], acc[ma][nb], 0, 0, 0);
    asm volatile("" ::: "memory");
    __builtin_amdgcn_s_barrier();
  }

#pragma unroll
  for (int ma = 0; ma < 4; ma++) {
    int lrowBase = wr * 64 + ma * 16 + lk * 4;
#pragma unroll
    for (int nb = 0; nb < 2; nb++) {
      int col = ct * 128 + wc * 32 + nb * 16 + lm;
#pragma unroll
      for (int rr = 0; rr < 4; rr++) {
        int lrow = lrowBase + rr;
        if (lrow < nrows)
          og[(size_t)(grow0 + lrow) * HD + col] = f2bf(acc[ma][nb][rr]);
      }
    }
  }
}

// ---------------- combine ----------------
__global__ void k_combine(const unsigned short* __restrict__ og, float* __restrict__ out,
                          const Ctl* __restrict__ ctl) {
  int tok = blockIdx.x;
  int tid = threadIdx.x;
  int p0 = ctl->pos[tok][0], p1 = ctl->pos[tok][1];
  float w0 = ctl->topW[tok][0], w1 = ctl->topW[tok][1];
  uint2 a = *(const uint2*)(og + (size_t)p0 * HD + tid * 4);
  uint2 b = *(const uint2*)(og + (size_t)p1 * HD + tid * 4);
  float4 o;
  o.x = w0 * bf2f((unsigned short)(a.x & 0xffffu)) + w1 * bf2f((unsigned short)(b.x & 0xffffu));
  o.y = w0 * bf2f((unsigned short)(a.x >> 16))     + w1 * bf2f((unsigned short)(b.x >> 16));
  o.z = w0 * bf2f((unsigned short)(a.y & 0xffffu)) + w1 * bf2f((unsigned short)(b.y & 0xffffu));
  o.w = w0 * bf2f((unsigned short)(a.y >> 16))     + w1 * bf2f((unsigned short)(b.y >> 16));
  *(float4*)(out + (size_t)tok * HD + tid * 4) = o;
}

extern "C" void kernel_launch(void* const* d_in, const int* in_sizes, int n_in,
                              void* d_out, int out_size, void* d_ws, size_t ws_size,
                              hipStream_t stream) {
  const float* x  = (const float*)d_in[0];   // [4,1024,1024]
  const float* gw = (const float*)d_in[1];   // [1024,8]
  const float* w1 = (const float*)d_in[2];   // [8,1024,2048]
  const float* w2 = (const float*)d_in[3];   // [8,2048,1024]
  const float* w3 = (const float*)d_in[4];   // [8,1024,2048]
  float* out = (float*)d_out;

  char* ws = (char*)d_ws;
  unsigned short* hg  = (unsigned short*)(ws);                         // 32 MB
  unsigned short* og  = (unsigned short*)(ws + (size_t)(32u << 20));   // 16 MB
  unsigned short* xb  = (unsigned short*)(ws + (size_t)(48u << 20));   // 8 MB
  unsigned short* wAt = (unsigned short*)(ws + (size_t)(56u << 20));   // 32 MB (w1t, then w2t)
  unsigned short* wBt = (unsigned short*)(ws + (size_t)(88u << 20));   // 32 MB (w3t)
  Ctl* ctl = (Ctl*)(ws + (size_t)(120u << 20));

  k_prep<<<dim3(8192), 256, 0, stream>>>(w1, w3, wAt, wBt);
  k_router<<<dim3(MTOK / 4), 256, 0, stream>>>(x, gw, xb, ctl);
  k_count<<<dim3(MTOK / 512), 512, 0, stream>>>(ctl);
  k_setup<<<1, 64, 0, stream>>>(ctl);
  k_scatter<<<dim3(MTOK / 512), 512, 0, stream>>>(ctl);
  k_gemm1<<<dim3(MAXT * (FD / 128)), 512, 0, stream>>>(xb, wAt, wBt, hg, ctl);
  k_tr<<<dim3(8 * 32 * 16), 256, 0, stream>>>(w2, wAt, FD, HD);   // w2t reuses w1t space
  k_gemm2<<<dim3(MAXT * (HD / 128)), 512, 0, stream>>>(hg, wAt, og, ctl);
  k_combine<<<dim3(MTOK), 256, 0, stream>>>(og, out, ctl);
}